// Round 1
// baseline (377.185 us; speedup 1.0000x reference)
//
#include <hip/hip_runtime.h>

// DigitCaps routing, fully fused (u_hat never materialized).
// B=512 batch, R=1152 routes, J=10 capsules, O=16 out-ch, I=8 in-ch.
// s[b,jo]   = sum_{r,i} x[b,r,i] * c[r,j] * W[r,j,o,i]      (GEMM 512x9216x160)
// v         = squash(s) = s*|s|/(1+s^2)
// b_upd[r,j]= (1/B) sum_{i,o} W[r,j,o,i] * M[r,i,jo],  M[r]=x[:,r,:]^T @ V
// c         = softmax over r (per j)
//
// ws layout (floats): bias[11520] | c[11520] | v[81920] | part[16*81920]
// total = 1,415,680 floats = 5.67 MB.

#define B_   512
#define R_   1152
#define J_   10
#define O_   16
#define I_   8
#define JO_  160
#define KS_  16   // k-splits for the s-GEMM
#define RK_  72   // routes per k-split (16*72 = 1152)
#define RC_  8    // routes staged per chunk
#define BT_  16   // batch tile per block (s-GEMM)

__device__ __forceinline__ int swz(int f4) { return f4 ^ ((f4 >> 3) & 7); }

__global__ __launch_bounds__(256) void init_kernel(float* __restrict__ bias,
                                                   float* __restrict__ c) {
  int idx = blockIdx.x * 256 + threadIdx.x;
  if (idx < R_ * J_) {
    bias[idx] = 0.0f;
    c[idx] = 1.0f / (float)R_;
  }
}

// grid (32 b-tiles, 16 k-splits), block 256.
// Each block: 16 batches x 160 outputs over 72 routes -> part[ks][b][jo].
__global__ __launch_bounds__(256) void s_partial_kernel(
    const float* __restrict__ x, const float* __restrict__ W,
    const float* __restrict__ c, float* __restrict__ part) {
  __shared__ float4 wcs4[RC_ * 320];      // 8 r * 1280 floats (c-folded W), 40KB
  __shared__ float4 xs4[RC_ * BT_ * 2];   // 8 r * 16 b * 8 floats, 4KB

  const int tid = threadIdx.x;
  const int bt = blockIdx.x, ks = blockIdx.y;
  const int bg = tid >> 5;    // 0..7 -> batches {2bg, 2bg+1}
  const int jog = tid & 31;   // 0..31 -> jo slots jog*5..jog*5+4
  const int b0 = bt * BT_;

  const float4* __restrict__ W4 = (const float4*)W;
  const float4* __restrict__ x4 = (const float4*)x;

  float acc[2][5] = {};

  for (int ch = 0; ch < RK_ / RC_; ++ch) {
    const int r0 = ks * RK_ + ch * RC_;
    // ---- stage x tile: 256 float4, one per thread (256B contiguous per b)
    {
      int bb = tid >> 4;
      int q = tid & 15;
      int rr = q >> 1, half = q & 1;
      xs4[(rr * BT_ + bb) * 2 + half] =
          x4[(b0 + bb) * 2304 + (r0 + rr) * 2 + half];
    }
    // ---- stage W*c tile: 2560 float4 contiguous, 10 per thread, swizzled
    for (int q = 0; q < 10; ++q) {
      int idx4 = q * 256 + tid;          // < 2560
      int rr = idx4 / 320;
      int rem4 = idx4 - rr * 320;        // float4 index within route row
      int j = rem4 >> 5;                 // 32 float4 per j
      float4 val = W4[(r0 + rr) * 320 + rem4];
      float cs = c[(r0 + rr) * 10 + j];
      val.x *= cs; val.y *= cs; val.z *= cs; val.w *= cs;
      wcs4[rr * 320 + swz(rem4)] = val;
    }
    __syncthreads();
    // ---- accumulate: per route 2 batches x 5 jo x 8 i
    for (int rr = 0; rr < RC_; ++rr) {
      const float4 xa0 = xs4[(rr * BT_ + 2 * bg) * 2 + 0];
      const float4 xa1 = xs4[(rr * BT_ + 2 * bg) * 2 + 1];
      const float4 xb0 = xs4[(rr * BT_ + 2 * bg + 1) * 2 + 0];
      const float4 xb1 = xs4[(rr * BT_ + 2 * bg + 1) * 2 + 1];
#pragma unroll
      for (int u = 0; u < 5; ++u) {
        int jo = jog * 5 + u;
        float4 w0 = wcs4[rr * 320 + swz(jo * 2)];
        float4 w1 = wcs4[rr * 320 + swz(jo * 2 + 1)];
        acc[0][u] += xa0.x * w0.x + xa0.y * w0.y + xa0.z * w0.z + xa0.w * w0.w
                   + xa1.x * w1.x + xa1.y * w1.y + xa1.z * w1.z + xa1.w * w1.w;
        acc[1][u] += xb0.x * w0.x + xb0.y * w0.y + xb0.z * w0.z + xb0.w * w0.w
                   + xb1.x * w1.x + xb1.y * w1.y + xb1.z * w1.z + xb1.w * w1.w;
      }
    }
    __syncthreads();
  }
#pragma unroll
  for (int u = 0; u < 5; ++u) {
    int jo = jog * 5 + u;
    part[(ks * B_ + (b0 + 2 * bg)) * JO_ + jo] = acc[0][u];
    part[(ks * B_ + (b0 + 2 * bg + 1)) * JO_ + jo] = acc[1][u];
  }
}

// reduce k-splits, squash, write v (and final output)
__global__ __launch_bounds__(256) void squash_kernel(
    const float* __restrict__ part, float* __restrict__ v,
    float* __restrict__ out) {
  int t = blockIdx.x * 256 + threadIdx.x;  // < 81920
  float s = 0.0f;
#pragma unroll
  for (int ks = 0; ks < KS_; ++ks) s += part[ks * B_ * JO_ + t];
  float val = s * fabsf(s) / (1.0f + s * s);
  v[t] = val;
  if (out) out[t] = val;
}

// grid 288 (4 routes each), block 256.
// M[r,i,jo] = sum_b x[b,r,i]*v[b,jo]; bias[r,j] += (1/B) sum_{i,o} W*M
__global__ __launch_bounds__(256) void agreement_kernel(
    const float* __restrict__ x, const float* __restrict__ W,
    const float* __restrict__ v, float* __restrict__ bias) {
  __shared__ float sm[5120 + 1024];  // vs [0,5120) | xs [5120,6144); M aliases vs
  float* vs = sm;
  float* xs = sm + 5120;
  float4* vs4 = (float4*)vs;
  float4* xs4 = (float4*)xs;

  const int tid = threadIdx.x;
  const int i = tid >> 5;     // 0..7
  const int jog = tid & 31;   // jo slots jog + 32u (conflict-free: 160%32==0)
  const int rbase = blockIdx.x * 4;

  const float4* __restrict__ x4 = (const float4*)x;
  const float4* __restrict__ v4 = (const float4*)v;

  float macc[4][5] = {};

  for (int ch = 0; ch < 16; ++ch) {
    int b0 = ch * 32;
    __syncthreads();  // previous chunk's reads done before overwrite
    {
      int r = tid >> 6;
      int q = tid & 63;
      int bb = q >> 1, half = q & 1;
      xs4[(r * 32 + bb) * 2 + half] =
          x4[(b0 + bb) * 2304 + (rbase + r) * 2 + half];
    }
    for (int q = 0; q < 5; ++q) {
      int idx4 = q * 256 + tid;  // < 1280
      int bb = idx4 / 40;
      int rem4 = idx4 - bb * 40;
      vs4[bb * 40 + rem4] = v4[(b0 + bb) * 40 + rem4];
    }
    __syncthreads();
    for (int bb = 0; bb < 32; ++bb) {
      float xv0 = xs[(0 * 32 + bb) * 8 + i];
      float xv1 = xs[(1 * 32 + bb) * 8 + i];
      float xv2 = xs[(2 * 32 + bb) * 8 + i];
      float xv3 = xs[(3 * 32 + bb) * 8 + i];
#pragma unroll
      for (int u = 0; u < 5; ++u) {
        float vv = vs[bb * 160 + jog + 32 * u];
        macc[0][u] += xv0 * vv;
        macc[1][u] += xv1 * vv;
        macc[2][u] += xv2 * vv;
        macc[3][u] += xv3 * vv;
      }
    }
  }
  __syncthreads();
#pragma unroll
  for (int r = 0; r < 4; ++r)
#pragma unroll
    for (int u = 0; u < 5; ++u)
      sm[r * 1280 + i * 160 + jog + 32 * u] = macc[r][u];
  __syncthreads();
  if (tid < 40) {
    int rr = tid / 10, j = tid - rr * 10;
    float sum = 0.0f;
    for (int o = 0; o < O_; ++o)
      for (int ii = 0; ii < I_; ++ii)
        sum += W[((rbase + rr) * 10 + j) * 128 + o * 8 + ii] *
               sm[rr * 1280 + ii * 160 + j * 16 + o];
    bias[(rbase + rr) * 10 + j] += sum * (1.0f / (float)B_);
  }
}

// grid 10 (one j per block), softmax over r, fixed-order tree reductions
__global__ __launch_bounds__(256) void softmax_kernel(
    const float* __restrict__ bias, float* __restrict__ c) {
  __shared__ float red[256];
  const int j = blockIdx.x;
  const int tid = threadIdx.x;
  float m = -1e30f;
  for (int r = tid; r < R_; r += 256) m = fmaxf(m, bias[r * 10 + j]);
  red[tid] = m;
  __syncthreads();
  for (int s = 128; s > 0; s >>= 1) {
    if (tid < s) red[tid] = fmaxf(red[tid], red[tid + s]);
    __syncthreads();
  }
  m = red[0];
  __syncthreads();
  float sum = 0.0f;
  for (int r = tid; r < R_; r += 256) sum += expf(bias[r * 10 + j] - m);
  red[tid] = sum;
  __syncthreads();
  for (int s = 128; s > 0; s >>= 1) {
    if (tid < s) red[tid] += red[tid + s];
    __syncthreads();
  }
  float inv = 1.0f / red[0];
  for (int r = tid; r < R_; r += 256)
    c[r * 10 + j] = expf(bias[r * 10 + j] - m) * inv;
}

extern "C" void kernel_launch(void* const* d_in, const int* in_sizes, int n_in,
                              void* d_out, int out_size, void* d_ws,
                              size_t ws_size, hipStream_t stream) {
  const float* x = (const float*)d_in[0];  // [512,1152,8]
  const float* W = (const float*)d_in[1];  // [1152,10,16,8]
  float* out = (float*)d_out;              // [512,10,16,1]
  float* ws = (float*)d_ws;

  float* bias = ws;              // 11520
  float* c    = ws + 11520;      // 11520
  float* v    = ws + 23040;      // 81920
  float* part = ws + 104960;     // 16*81920 = 1,310,720

  init_kernel<<<45, 256, 0, stream>>>(bias, c);

  for (int it = 0; it < 3; ++it) {
    s_partial_kernel<<<dim3(32, 16), 256, 0, stream>>>(x, W, c, part);
    squash_kernel<<<320, 256, 0, stream>>>(part, v,
                                           (it == 2) ? out : nullptr);
    if (it < 2) {
      agreement_kernel<<<288, 256, 0, stream>>>(x, W, v, bias);
      softmax_kernel<<<10, 256, 0, stream>>>(bias, c);
    }
  }
}